// Round 6
// baseline (476.678 us; speedup 1.0000x reference)
//
#include <hip/hip_runtime.h>
#include <cstdint>

#define NN 100000
#define NE 1600000
#define FI 602
#define FIP 640           // padded K for k1 (zero rows 602..639)
#define DD 32
#define CC 41
#define BN_EPS 1e-5f
#define SCAN_B 98         // ceil(NN/1024)
#define K1CH 16
#define K1NCH 38          // 38*16 = 608 >= 602

__device__ __forceinline__ void atomAdd(float* p, float v) {
#ifdef __HIP_PLATFORM_AMD__
  unsafeAtomicAdd(p, v);
#else
  atomicAdd(p, v);
#endif
}

// ---------------- K0: Mp[640x32] = lin1_w @ nn1_w1 (zero-padded) ; cvec ; zero stats
__global__ __launch_bounds__(256) void k0_prep(
    const float* __restrict__ lin1_w, const float* __restrict__ lin1_b,
    const float* __restrict__ nn1_w1,
    float* __restrict__ Mp, float* __restrict__ cvec,
    float* __restrict__ stats1, float* __restrict__ stats2) {
  int o = blockIdx.x * 256 + threadIdx.x;
  if (o < FIP * DD) {
    int k = o >> 5, j = o & 31;
    float s = 0.f;
    if (k < FI) {
      #pragma unroll 4
      for (int c = 0; c < 2 * DD; ++c) s = fmaf(lin1_w[k * (2 * DD) + c], nn1_w1[c * DD + j], s);
    }
    Mp[o] = s;
  }
  if (blockIdx.x == 0) {
    int t = threadIdx.x;
    if (t < DD) {
      float s = 0.f;
      for (int c = 0; c < 2 * DD; ++c) s = fmaf(lin1_b[c], nn1_w1[c * DD + t], s);
      cvec[t] = s;
    }
    if (t >= 128 && t < 192) stats1[t - 128] = 0.f;
    if (t >= 192) stats2[t - 192] = 0.f;
  }
}

// ---------------- CSR build: histogram -> 3-phase scan -> fill
__global__ __launch_bounds__(256) void k_hist(const int* __restrict__ ei, int* __restrict__ deg) {
  int e = blockIdx.x * 256 + threadIdx.x;
  if (e < NE) atomicAdd(&deg[ei[NE + e]], 1);
}

__global__ __launch_bounds__(1024) void k_scan1(const int* __restrict__ deg, int* __restrict__ bsum) {
  __shared__ int wsum[16];
  int gid = blockIdx.x * 1024 + threadIdx.x;
  int v = (gid < NN) ? deg[gid] : 0;
  #pragma unroll
  for (int off = 1; off < 64; off <<= 1) v += __shfl_xor(v, off);
  int wave = threadIdx.x >> 6, lane = threadIdx.x & 63;
  if (lane == 0) wsum[wave] = v;
  __syncthreads();
  if (threadIdx.x == 0) {
    int s = 0;
    #pragma unroll
    for (int i = 0; i < 16; ++i) s += wsum[i];
    bsum[blockIdx.x] = s;
  }
}

__global__ __launch_bounds__(128) void k_scan2(int* __restrict__ bsum, int* __restrict__ rowstart) {
  __shared__ int ps[128];
  int t = threadIdx.x;
  int v = (t < SCAN_B) ? bsum[t] : 0;
  ps[t] = v;
  __syncthreads();
  #pragma unroll
  for (int off = 1; off < 128; off <<= 1) {
    int u = (t >= off) ? ps[t - off] : 0;
    __syncthreads();
    ps[t] += u;
    __syncthreads();
  }
  if (t < SCAN_B) bsum[t] = ps[t] - v;   // exclusive block offsets
  if (t == 0) rowstart[NN] = NE;
}

__global__ __launch_bounds__(1024) void k_scan3(int* __restrict__ deg_cursor,
                                                const int* __restrict__ bsum,
                                                int* __restrict__ rowstart) {
  __shared__ int ps[1024];
  int gid = blockIdx.x * 1024 + threadIdx.x;
  int t = threadIdx.x;
  int v = (gid < NN) ? deg_cursor[gid] : 0;
  ps[t] = v;
  __syncthreads();
  #pragma unroll
  for (int off = 1; off < 1024; off <<= 1) {
    int u = (t >= off) ? ps[t - off] : 0;
    __syncthreads();
    ps[t] += u;
    __syncthreads();
  }
  int excl = ps[t] - v + bsum[blockIdx.x];
  if (gid < NN) {
    rowstart[gid] = excl;
    deg_cursor[gid] = excl;   // becomes fill cursor
  }
}

__global__ __launch_bounds__(256) void k_fill(const int* __restrict__ ei,
                                              int* __restrict__ cursor,
                                              int* __restrict__ srcidx) {
  int e = blockIdx.x * 256 + threadIdx.x;
  if (e >= NE) return;
  int s = ei[e], d = ei[NE + e];
  int p = atomicAdd(&cursor[d], 1);
  srcidx[p] = s;
}

// ---------------- gather (optionally fused BN on the gathered operand)
template <bool BN>
__global__ __launch_bounds__(256) void k_gather_t(const int* __restrict__ rowstart,
                                                  const int* __restrict__ srcidx,
                                                  const float* __restrict__ src,
                                                  const float* __restrict__ bnp,
                                                  float* __restrict__ agg) {
  int gid = blockIdx.x * 256 + threadIdx.x;
  int n = gid >> 3, q = gid & 7;
  if (n >= NN) return;
  float4 mu, rs, be;
  if (BN) {
    mu = *(const float4*)&bnp[q * 4];
    rs = *(const float4*)&bnp[DD + q * 4];
    be = *(const float4*)&bnp[2 * DD + q * 4];
  }
  int beg = rowstart[n], end = rowstart[n + 1];
  float4 a0 = make_float4(0.f, 0.f, 0.f, 0.f);
  float4 a1 = a0, a2 = a0, a3 = a0;
  int i = beg;
  for (; i + 4 <= end; i += 4) {
    int s0 = srcidx[i], s1 = srcidx[i + 1], s2 = srcidx[i + 2], s3 = srcidx[i + 3];
    float4 v0 = *(const float4*)&src[(size_t)s0 * DD + q * 4];
    float4 v1 = *(const float4*)&src[(size_t)s1 * DD + q * 4];
    float4 v2 = *(const float4*)&src[(size_t)s2 * DD + q * 4];
    float4 v3 = *(const float4*)&src[(size_t)s3 * DD + q * 4];
    if (BN) {
      v0 = make_float4((v0.x - mu.x) * rs.x + be.x, (v0.y - mu.y) * rs.y + be.y,
                       (v0.z - mu.z) * rs.z + be.z, (v0.w - mu.w) * rs.w + be.w);
      v1 = make_float4((v1.x - mu.x) * rs.x + be.x, (v1.y - mu.y) * rs.y + be.y,
                       (v1.z - mu.z) * rs.z + be.z, (v1.w - mu.w) * rs.w + be.w);
      v2 = make_float4((v2.x - mu.x) * rs.x + be.x, (v2.y - mu.y) * rs.y + be.y,
                       (v2.z - mu.z) * rs.z + be.z, (v2.w - mu.w) * rs.w + be.w);
      v3 = make_float4((v3.x - mu.x) * rs.x + be.x, (v3.y - mu.y) * rs.y + be.y,
                       (v3.z - mu.z) * rs.z + be.z, (v3.w - mu.w) * rs.w + be.w);
    }
    a0.x += v0.x; a0.y += v0.y; a0.z += v0.z; a0.w += v0.w;
    a1.x += v1.x; a1.y += v1.y; a1.z += v1.z; a1.w += v1.w;
    a2.x += v2.x; a2.y += v2.y; a2.z += v2.z; a2.w += v2.w;
    a3.x += v3.x; a3.y += v3.y; a3.z += v3.z; a3.w += v3.w;
  }
  for (; i < end; ++i) {
    int s0 = srcidx[i];
    float4 v0 = *(const float4*)&src[(size_t)s0 * DD + q * 4];
    if (BN)
      v0 = make_float4((v0.x - mu.x) * rs.x + be.x, (v0.y - mu.y) * rs.y + be.y,
                       (v0.z - mu.z) * rs.z + be.z, (v0.w - mu.w) * rs.w + be.w);
    a0.x += v0.x; a0.y += v0.y; a0.z += v0.z; a0.w += v0.w;
  }
  float4 r = make_float4(a0.x + a1.x + a2.x + a3.x, a0.y + a1.y + a2.y + a3.y,
                         a0.z + a1.z + a2.z + a3.z, a0.w + a1.w + a2.w + a3.w);
  *(float4*)&agg[(size_t)n * DD + q * 4] = r;
}

// ---------------- K1 v4: z = x @ Mp + cvec
// 256 threads, 128 rows/block. Wave w = col group (8 cols); lane owns rows
// {lane, lane+64}: acc[2][8]. M chunk staged in LDS (broadcast ds_read_b128,
// no scalar-load stalls); x tile transposed xs[k][row] -> stride-1 reads.
// Register prefetch + double buffer, one barrier per chunk.
__global__ __launch_bounds__(256) void k1_lin1(
    const float* __restrict__ x, const float* __restrict__ Mp,
    const float* __restrict__ cvec, float* __restrict__ z) {
  __shared__ float xs[2][K1CH][132];
  __shared__ float ms[2][K1CH][36];
  const int tid = threadIdx.x;
  const int wave = tid >> 6, lane = tid & 63;
  const int q8 = wave * 8;
  const int row0 = blockIdx.x * 128;
  // x staging: 512 float4 slots (128 rows x 4 quarters); this thread: tid, tid+256
  const int ra = tid >> 2, ka = (tid & 3) * 4;
  const int rb = ra + 64, kb = ka;
  const int gra = row0 + ra, grb = row0 + rb;
  // M staging: 128 float4 slots (16 k x 8 quarters); threads 0..127
  const int mk = tid >> 3, mj = (tid & 7) * 4;

  float acc0[8] = {}, acc1[8] = {};
  float4 pa, pb, pm;

  // prologue: chunk 0 into regs, then buf 0 (k = 0..15 < FI, unguarded cols)
  pa = make_float4(0.f, 0.f, 0.f, 0.f);
  pb = pa;
  if (gra < NN) pa = *(const float4*)&x[(size_t)gra * FI + ka];
  if (grb < NN) pb = *(const float4*)&x[(size_t)grb * FI + kb];
  if (tid < 128) pm = *(const float4*)&Mp[mk * DD + mj];
  {
    xs[0][ka + 0][ra] = pa.x; xs[0][ka + 1][ra] = pa.y;
    xs[0][ka + 2][ra] = pa.z; xs[0][ka + 3][ra] = pa.w;
    xs[0][kb + 0][rb] = pb.x; xs[0][kb + 1][rb] = pb.y;
    xs[0][kb + 2][rb] = pb.z; xs[0][kb + 3][rb] = pb.w;
    if (tid < 128) *(float4*)&ms[0][mk][mj] = pm;
  }

  int cur = 0;
  for (int c = 0; c < K1NCH; ++c) {
    if (c + 1 < K1NCH) {
      const int kbase = (c + 1) * K1CH;
      pa = make_float4(0.f, 0.f, 0.f, 0.f);
      pb = pa;
      int gk = kbase + ka;
      if (gra < NN) {
        if (gk + 3 < FI) {
          pa = *(const float4*)&x[(size_t)gra * FI + gk];
        } else {
          if (gk + 0 < FI) pa.x = x[(size_t)gra * FI + gk + 0];
          if (gk + 1 < FI) pa.y = x[(size_t)gra * FI + gk + 1];
          if (gk + 2 < FI) pa.z = x[(size_t)gra * FI + gk + 2];
        }
      }
      if (grb < NN) {
        if (gk + 3 < FI) {
          pb = *(const float4*)&x[(size_t)grb * FI + gk];
        } else {
          if (gk + 0 < FI) pb.x = x[(size_t)grb * FI + gk + 0];
          if (gk + 1 < FI) pb.y = x[(size_t)grb * FI + gk + 1];
          if (gk + 2 < FI) pb.z = x[(size_t)grb * FI + gk + 2];
        }
      }
      if (tid < 128) pm = *(const float4*)&Mp[(kbase + mk) * DD + mj];  // Mp padded: safe
    }
    __syncthreads();   // buf[cur] fully written (and prior reads of buf[cur^1] done)
    #pragma unroll
    for (int kk = 0; kk < K1CH; ++kk) {
      float x0 = xs[cur][kk][lane];
      float x1 = xs[cur][kk][64 + lane];
      float4 m0 = *(const float4*)&ms[cur][kk][q8];
      float4 m1 = *(const float4*)&ms[cur][kk][q8 + 4];
      acc0[0] = fmaf(x0, m0.x, acc0[0]); acc1[0] = fmaf(x1, m0.x, acc1[0]);
      acc0[1] = fmaf(x0, m0.y, acc0[1]); acc1[1] = fmaf(x1, m0.y, acc1[1]);
      acc0[2] = fmaf(x0, m0.z, acc0[2]); acc1[2] = fmaf(x1, m0.z, acc1[2]);
      acc0[3] = fmaf(x0, m0.w, acc0[3]); acc1[3] = fmaf(x1, m0.w, acc1[3]);
      acc0[4] = fmaf(x0, m1.x, acc0[4]); acc1[4] = fmaf(x1, m1.x, acc1[4]);
      acc0[5] = fmaf(x0, m1.y, acc0[5]); acc1[5] = fmaf(x1, m1.y, acc1[5]);
      acc0[6] = fmaf(x0, m1.z, acc0[6]); acc1[6] = fmaf(x1, m1.z, acc1[6]);
      acc0[7] = fmaf(x0, m1.w, acc0[7]); acc1[7] = fmaf(x1, m1.w, acc1[7]);
    }
    if (c + 1 < K1NCH) {
      int nxt = cur ^ 1;
      xs[nxt][ka + 0][ra] = pa.x; xs[nxt][ka + 1][ra] = pa.y;
      xs[nxt][ka + 2][ra] = pa.z; xs[nxt][ka + 3][ra] = pa.w;
      xs[nxt][kb + 0][rb] = pb.x; xs[nxt][kb + 1][rb] = pb.y;
      xs[nxt][kb + 2][rb] = pb.z; xs[nxt][kb + 3][rb] = pb.w;
      if (tid < 128) *(float4*)&ms[nxt][mk][mj] = pm;
    }
    cur ^= 1;
  }

  const float4 cv0 = *(const float4*)&cvec[q8];
  const float4 cv1 = *(const float4*)&cvec[q8 + 4];
  int rowA = row0 + lane, rowB = row0 + 64 + lane;
  if (rowA < NN) {
    float* zp = &z[(size_t)rowA * DD + q8];
    *(float4*)&zp[0] = make_float4(acc0[0] + cv0.x, acc0[1] + cv0.y, acc0[2] + cv0.z, acc0[3] + cv0.w);
    *(float4*)&zp[4] = make_float4(acc0[4] + cv1.x, acc0[5] + cv1.y, acc0[6] + cv1.z, acc0[7] + cv1.w);
  }
  if (rowB < NN) {
    float* zp = &z[(size_t)rowB * DD + q8];
    *(float4*)&zp[0] = make_float4(acc1[0] + cv0.x, acc1[1] + cv0.y, acc1[2] + cv0.z, acc1[3] + cv0.w);
    *(float4*)&zp[4] = make_float4(acc1[4] + cv1.x, acc1[5] + cv1.y, acc1[6] + cv1.z, acc1[7] + cv1.w);
  }
}

// ---------------- K3: g1 = relu(z+agg+b1) @ w2 + b2 ; stats
__global__ __launch_bounds__(256) void k3_mlp1(
    const float* __restrict__ z, const float* __restrict__ agg,
    const float* __restrict__ w2, const float* __restrict__ b1, const float* __restrict__ b2,
    float* __restrict__ g1, float* __restrict__ stats) {
  __shared__ float us[256][DD + 1];
  __shared__ float w2s[DD][DD];
  __shared__ float ps[4][2 * DD];
  const int tid = threadIdx.x;
  const int n0 = blockIdx.x * 256;
  for (int i = tid; i < DD * DD; i += 256) w2s[i >> 5][i & 31] = w2[i];
  #pragma unroll
  for (int i = 0; i < 32; ++i) {
    int l = tid + i * 256;
    int r = l >> 5, c = l & 31;
    float v = 0.f;
    if (n0 + r < NN) {
      size_t gi = (size_t)(n0 + r) * DD + c;
      v = z[gi] + agg[gi];
    }
    us[r][c] = v;
  }
  __syncthreads();
  float t[DD];
  #pragma unroll
  for (int k = 0; k < DD; ++k) t[k] = fmaxf(us[tid][k] + b1[k], 0.f);
  float g[DD];
  #pragma unroll
  for (int j = 0; j < DD; ++j) g[j] = b2[j];
  #pragma unroll
  for (int k = 0; k < DD; ++k) {
    float tv = t[k];
    #pragma unroll
    for (int j = 0; j < DD; ++j) g[j] = fmaf(tv, w2s[k][j], g[j]);
  }
  bool valid = (n0 + tid) < NN;
  #pragma unroll
  for (int j = 0; j < DD; ++j) us[tid][j] = g[j];
  int wave = tid >> 6, lane = tid & 63;
  #pragma unroll
  for (int j = 0; j < DD; ++j) {
    float v = valid ? g[j] : 0.f;
    float qq = v * v;
    #pragma unroll
    for (int off = 1; off < 64; off <<= 1) { v += __shfl_xor(v, off); qq += __shfl_xor(qq, off); }
    if (lane == 0) { ps[wave][j] = v; ps[wave][DD + j] = qq; }
  }
  __syncthreads();
  if (tid < 2 * DD)
    atomAdd(&stats[tid], ps[0][tid] + ps[1][tid] + ps[2][tid] + ps[3][tid]);
  #pragma unroll
  for (int i = 0; i < 32; ++i) {
    int l = tid + i * 256;
    int r = l >> 5, c = l & 31;
    if (n0 + r < NN) g1[(size_t)(n0 + r) * DD + c] = us[r][c];
  }
}

// ---------------- K3b: finalize BN1 params
__global__ void k3b_bn(const float* __restrict__ stats, const float* __restrict__ gamma,
                       const float* __restrict__ beta, float* __restrict__ bnp) {
  int t = threadIdx.x;
  if (t < DD) {
    float mu = stats[t] * (1.f / NN);
    float var = stats[DD + t] * (1.f / NN) - mu * mu;
    bnp[t] = mu;
    bnp[DD + t] = rsqrtf(var + BN_EPS) * gamma[t];
    bnp[2 * DD + t] = beta[t];
  }
}

// ---------------- K6: g2 = relu((bn1(g1)+agg2)@w1+b1)@w2+b2 ; stats2
__global__ __launch_bounds__(256) void k6_mlp2(
    const float* __restrict__ g1, const float* __restrict__ agg,
    const float* __restrict__ bnp,
    const float* __restrict__ w1, const float* __restrict__ b1,
    const float* __restrict__ w2, const float* __restrict__ b2,
    float* __restrict__ g2, float* __restrict__ stats) {
  __shared__ float us[256][DD + 1];
  __shared__ float w1s[DD][DD];
  __shared__ float w2s[DD][DD];
  __shared__ float ps[4][2 * DD];
  const int tid = threadIdx.x;
  const int n0 = blockIdx.x * 256;
  for (int i = tid; i < DD * DD; i += 256) { w1s[i >> 5][i & 31] = w1[i]; w2s[i >> 5][i & 31] = w2[i]; }
  #pragma unroll
  for (int i = 0; i < 32; ++i) {
    int l = tid + i * 256;
    int r = l >> 5, c = l & 31;
    float v = 0.f;
    if (n0 + r < NN) {
      size_t gi = (size_t)(n0 + r) * DD + c;
      v = (g1[gi] - bnp[c]) * bnp[DD + c] + bnp[2 * DD + c] + agg[gi];
    }
    us[r][c] = v;
  }
  __syncthreads();
  float t1[DD];
  #pragma unroll
  for (int j = 0; j < DD; ++j) t1[j] = b1[j];
  #pragma unroll
  for (int k = 0; k < DD; ++k) {
    float uv = us[tid][k];
    #pragma unroll
    for (int j = 0; j < DD; ++j) t1[j] = fmaf(uv, w1s[k][j], t1[j]);
  }
  #pragma unroll
  for (int j = 0; j < DD; ++j) t1[j] = fmaxf(t1[j], 0.f);
  float g[DD];
  #pragma unroll
  for (int j = 0; j < DD; ++j) g[j] = b2[j];
  #pragma unroll
  for (int k = 0; k < DD; ++k) {
    float tv = t1[k];
    #pragma unroll
    for (int j = 0; j < DD; ++j) g[j] = fmaf(tv, w2s[k][j], g[j]);
  }
  bool valid = (n0 + tid) < NN;
  #pragma unroll
  for (int j = 0; j < DD; ++j) us[tid][j] = g[j];
  int wave = tid >> 6, lane = tid & 63;
  #pragma unroll
  for (int j = 0; j < DD; ++j) {
    float v = valid ? g[j] : 0.f;
    float qq = v * v;
    #pragma unroll
    for (int off = 1; off < 64; off <<= 1) { v += __shfl_xor(v, off); qq += __shfl_xor(qq, off); }
    if (lane == 0) { ps[wave][j] = v; ps[wave][DD + j] = qq; }
  }
  __syncthreads();
  if (tid < 2 * DD)
    atomAdd(&stats[tid], ps[0][tid] + ps[1][tid] + ps[2][tid] + ps[3][tid]);
  #pragma unroll
  for (int i = 0; i < 32; ++i) {
    int l = tid + i * 256;
    int r = l >> 5, c = l & 31;
    if (n0 + r < NN) g2[(size_t)(n0 + r) * DD + c] = us[r][c];
  }
}

// ---------------- K7: out = relu(bn2(g2)@fc1+b)@fc2+b
__global__ __launch_bounds__(256) void k7_head(
    const float* __restrict__ g2, const float* __restrict__ stats2,
    const float* __restrict__ bn2_g, const float* __restrict__ bn2_b,
    const float* __restrict__ fc1_w, const float* __restrict__ fc1_b,
    const float* __restrict__ fc2_w, const float* __restrict__ fc2_b,
    float* __restrict__ out) {
  __shared__ float buf[256 * 42];
  __shared__ float fc1s[DD * DD];
  __shared__ float fc2s[DD * CC];
  __shared__ float mu2[DD], rsg2[DD], bet2[DD];
  const int tid = threadIdx.x;
  const int n0 = blockIdx.x * 256;
  if (tid < DD) {
    float mu = stats2[tid] * (1.f / NN);
    float var = stats2[DD + tid] * (1.f / NN) - mu * mu;
    mu2[tid] = mu;
    rsg2[tid] = rsqrtf(var + BN_EPS) * bn2_g[tid];
    bet2[tid] = bn2_b[tid];
  }
  for (int i = tid; i < DD * DD; i += 256) fc1s[i] = fc1_w[i];
  for (int i = tid; i < DD * CC; i += 256) fc2s[i] = fc2_w[i];
  __syncthreads();
  #pragma unroll
  for (int i = 0; i < 32; ++i) {
    int l = tid + i * 256;
    int r = l >> 5, c = l & 31;
    float v = 0.f;
    if (n0 + r < NN) v = (g2[(size_t)(n0 + r) * DD + c] - mu2[c]) * rsg2[c] + bet2[c];
    buf[r * 33 + c] = v;
  }
  __syncthreads();
  float t[DD];
  #pragma unroll
  for (int j = 0; j < DD; ++j) t[j] = fc1_b[j];
  #pragma unroll
  for (int k = 0; k < DD; ++k) {
    float uv = buf[tid * 33 + k];
    #pragma unroll
    for (int j = 0; j < DD; ++j) t[j] = fmaf(uv, fc1s[k * DD + j], t[j]);
  }
  #pragma unroll
  for (int j = 0; j < DD; ++j) t[j] = fmaxf(t[j], 0.f);
  float o[CC];
  #pragma unroll
  for (int j = 0; j < CC; ++j) o[j] = fc2_b[j];
  #pragma unroll
  for (int k = 0; k < DD; ++k) {
    float tv = t[k];
    #pragma unroll
    for (int j = 0; j < CC; ++j) o[j] = fmaf(tv, fc2s[k * CC + j], o[j]);
  }
  __syncthreads();
  #pragma unroll
  for (int j = 0; j < CC; ++j) buf[tid * 42 + j] = o[j];
  __syncthreads();
  for (int i = 0; i < CC; ++i) {
    int l = tid + i * 256;
    int r = l / CC, c = l % CC;
    if (n0 + r < NN) out[(size_t)(n0 + r) * CC + c] = buf[r * 42 + c];
  }
}

extern "C" void kernel_launch(void* const* d_in, const int* in_sizes, int n_in,
                              void* d_out, int out_size, void* d_ws, size_t ws_size,
                              hipStream_t stream) {
  const float* x      = (const float*)d_in[0];
  const int*   ei     = (const int*)d_in[1];
  const float* lin1_w = (const float*)d_in[2];
  const float* lin1_b = (const float*)d_in[3];
  const float* nn1_w1 = (const float*)d_in[4];
  const float* nn1_b1 = (const float*)d_in[5];
  const float* nn1_w2 = (const float*)d_in[6];
  const float* nn1_b2 = (const float*)d_in[7];
  const float* bn1_g  = (const float*)d_in[8];
  const float* bn1_b  = (const float*)d_in[9];
  const float* nn2_w1 = (const float*)d_in[10];
  const float* nn2_b1 = (const float*)d_in[11];
  const float* nn2_w2 = (const float*)d_in[12];
  const float* nn2_b2 = (const float*)d_in[13];
  const float* bn2_g  = (const float*)d_in[14];
  const float* bn2_b  = (const float*)d_in[15];
  const float* fc1_w  = (const float*)d_in[16];
  const float* fc1_b  = (const float*)d_in[17];
  const float* fc2_w  = (const float*)d_in[18];
  const float* fc2_b  = (const float*)d_in[19];
  float* out = (float*)d_out;

  float* ws = (float*)d_ws;
  size_t nd = (size_t)NN * DD;
  float* A      = ws;            // z
  float* B      = ws + nd;       // agg1, then agg2
  float* Cb     = ws + 2 * nd;   // g1, then g2
  float* Mp     = ws + 3 * nd;   // 640*32 (padded)
  float* cvec   = Mp + FIP * DD;
  float* stats1 = cvec + 32;
  float* bnp1   = stats1 + 64;
  float* stats2 = bnp1 + 96;
  int*   rowstart = (int*)(stats2 + 64);         // NN+1
  int*   cursor   = rowstart + (NN + 1);         // NN (deg -> cursor)
  int*   srcidx   = cursor + NN;                 // NE
  int*   bsum     = srcidx + NE;                 // SCAN_B

  // CSR build
  hipMemsetAsync(cursor, 0, NN * sizeof(int), stream);
  k_hist<<<(NE + 255) / 256, 256, 0, stream>>>(ei, cursor);
  k_scan1<<<SCAN_B, 1024, 0, stream>>>(cursor, bsum);
  k_scan2<<<1, 128, 0, stream>>>(bsum, rowstart);
  k_scan3<<<SCAN_B, 1024, 0, stream>>>(cursor, bsum, rowstart);
  k_fill<<<(NE + 255) / 256, 256, 0, stream>>>(ei, cursor, srcidx);

  k0_prep<<<(FIP * DD + 255) / 256, 256, 0, stream>>>(lin1_w, lin1_b, nn1_w1, Mp, cvec, stats1, stats2);
  k1_lin1<<<(NN + 127) / 128, 256, 0, stream>>>(x, Mp, cvec, A);
  k_gather_t<false><<<(NN * 8 + 255) / 256, 256, 0, stream>>>(rowstart, srcidx, A, nullptr, B);
  k3_mlp1<<<(NN + 255) / 256, 256, 0, stream>>>(A, B, nn1_w2, nn1_b1, nn1_b2, Cb, stats1);
  k3b_bn<<<1, 64, 0, stream>>>(stats1, bn1_g, bn1_b, bnp1);
  k_gather_t<true><<<(NN * 8 + 255) / 256, 256, 0, stream>>>(rowstart, srcidx, Cb, bnp1, B);
  k6_mlp2<<<(NN + 255) / 256, 256, 0, stream>>>(Cb, B, bnp1, nn2_w1, nn2_b1, nn2_w2, nn2_b2, A, stats2);
  k7_head<<<(NN + 255) / 256, 256, 0, stream>>>(A, stats2, bn2_g, bn2_b, fc1_w, fc1_b, fc2_w, fc2_b, out);
}

// Round 7
// 362.551 us; speedup vs baseline: 1.3148x; 1.3148x over previous
//
#include <hip/hip_runtime.h>
#include <cstdint>

#define NN 100000
#define NE 1600000
#define FI 602
#define FIP 640           // padded K for k1 (zero rows 602..639)
#define DD 32
#define CC 41
#define BN_EPS 1e-5f
#define K1CH 16
#define K1NCH 38          // 38*16 = 608 >= 602

// bucketed CSR build
#define NPB 256                   // nodes per bucket (dst >> 8)
#define NB 391                    // ceil(NN/NPB)
#define EPT 13                    // edges per thread in hist/scatter
#define SCB 481                   // ceil(NE / (256*EPT))

__device__ __forceinline__ void atomAdd(float* p, float v) {
#ifdef __HIP_PLATFORM_AMD__
  unsafeAtomicAdd(p, v);
#else
  atomicAdd(p, v);
#endif
}

// ---------------- K0: Mp[640x32] = lin1_w @ nn1_w1 (zero-padded) ; cvec ; zero stats
__global__ __launch_bounds__(256) void k0_prep(
    const float* __restrict__ lin1_w, const float* __restrict__ lin1_b,
    const float* __restrict__ nn1_w1,
    float* __restrict__ Mp, float* __restrict__ cvec,
    float* __restrict__ stats1, float* __restrict__ stats2) {
  int o = blockIdx.x * 256 + threadIdx.x;
  if (o < FIP * DD) {
    int k = o >> 5, j = o & 31;
    float s = 0.f;
    if (k < FI) {
      #pragma unroll 4
      for (int c = 0; c < 2 * DD; ++c) s = fmaf(lin1_w[k * (2 * DD) + c], nn1_w1[c * DD + j], s);
    }
    Mp[o] = s;
  }
  if (blockIdx.x == 0) {
    int t = threadIdx.x;
    if (t < DD) {
      float s = 0.f;
      for (int c = 0; c < 2 * DD; ++c) s = fmaf(lin1_b[c], nn1_w1[c * DD + t], s);
      cvec[t] = s;
    }
    if (t >= 128 && t < 192) stats1[t - 128] = 0.f;
    if (t >= 192) stats2[t - 192] = 0.f;
  }
}

// ---------------- bucketed CSR build ----------------
__global__ __launch_bounds__(256) void kb_hist(const int* __restrict__ ei, int* __restrict__ bcount) {
  __shared__ int h[NB];
  const int t = threadIdx.x;
  for (int i = t; i < NB; i += 256) h[i] = 0;
  __syncthreads();
  const int base = blockIdx.x * (256 * EPT);
  #pragma unroll
  for (int i = 0; i < EPT; ++i) {
    int e = base + i * 256 + t;
    if (e < NE) atomicAdd(&h[ei[NE + e] >> 8], 1);
  }
  __syncthreads();
  for (int i = t; i < NB; i += 256) if (h[i]) atomicAdd(&bcount[i], h[i]);
}

__global__ __launch_bounds__(512) void kb_scan(const int* __restrict__ bcount,
                                               int* __restrict__ bbase,
                                               int* __restrict__ bcursor,
                                               int* __restrict__ rowstart) {
  __shared__ int ps[512];
  const int t = threadIdx.x;
  int v = (t < NB) ? bcount[t] : 0;
  ps[t] = v;
  __syncthreads();
  #pragma unroll
  for (int off = 1; off < 512; off <<= 1) {
    int u = (t >= off) ? ps[t - off] : 0;
    __syncthreads();
    ps[t] += u;
    __syncthreads();
  }
  int excl = ps[t] - v;
  if (t < NB) { bbase[t] = excl; bcursor[t] = excl; }
  if (t == 0) { bbase[NB] = NE; rowstart[NN] = NE; }
}

__global__ __launch_bounds__(256) void kb_scatter(const int* __restrict__ ei,
                                                  int* __restrict__ bcursor,
                                                  int* __restrict__ tsrc,
                                                  unsigned char* __restrict__ tdst) {
  __shared__ int cnt[NB];
  __shared__ int wbase[NB];
  const int t = threadIdx.x;
  for (int i = t; i < NB; i += 256) cnt[i] = 0;
  __syncthreads();
  const int base = blockIdx.x * (256 * EPT);
  int s[EPT], d[EPT];
  #pragma unroll
  for (int i = 0; i < EPT; ++i) {
    int e = base + i * 256 + t;
    if (e < NE) {
      s[i] = ei[e];
      d[i] = ei[NE + e];
      atomicAdd(&cnt[d[i] >> 8], 1);
    } else {
      s[i] = -1; d[i] = -1;
    }
  }
  __syncthreads();
  for (int i = t; i < NB; i += 256) wbase[i] = atomicAdd(&bcursor[i], cnt[i]);
  __syncthreads();
  #pragma unroll
  for (int i = 0; i < EPT; ++i) {
    if (d[i] >= 0) {
      int p = atomicAdd(&wbase[d[i] >> 8], 1);
      tsrc[p] = s[i];
      tdst[p] = (unsigned char)(d[i] & (NPB - 1));
    }
  }
}

__global__ __launch_bounds__(256) void kb_fine(const int* __restrict__ bbase,
                                               const int* __restrict__ tsrc,
                                               const unsigned char* __restrict__ tdst,
                                               int* __restrict__ rowstart,
                                               int* __restrict__ srcidx) {
  __shared__ int deg[NPB];
  __shared__ int cur[NPB];
  __shared__ int woff[4];
  const int b = blockIdx.x, t = threadIdx.x;
  const int beg = bbase[b], end = bbase[b + 1];
  deg[t] = 0;
  __syncthreads();
  for (int i = beg + t; i < end; i += 256) atomicAdd(&deg[tdst[i]], 1);
  __syncthreads();
  // exclusive scan over 256 degrees
  int v = deg[t];
  int lane = t & 63, wave = t >> 6;
  int inc = v;
  #pragma unroll
  for (int off = 1; off < 64; off <<= 1) {
    int u = __shfl_up(inc, off);
    if (lane >= off) inc += u;
  }
  if (lane == 63) woff[wave] = inc;
  __syncthreads();
  int wadd = 0;
  for (int w = 0; w < wave; ++w) wadd += woff[w];
  int excl = wadd + inc - v;
  int gnode = b * NPB + t;
  if (gnode < NN) rowstart[gnode] = beg + excl;
  cur[t] = beg + excl;
  __syncthreads();
  for (int i = beg + t; i < end; i += 256) {
    int p = atomicAdd(&cur[tdst[i]], 1);
    srcidx[p] = tsrc[i];
  }
}

// ---------------- gather (optionally fused BN on the gathered operand)
template <bool BN>
__global__ __launch_bounds__(256) void k_gather_t(const int* __restrict__ rowstart,
                                                  const int* __restrict__ srcidx,
                                                  const float* __restrict__ src,
                                                  const float* __restrict__ bnp,
                                                  float* __restrict__ agg) {
  int gid = blockIdx.x * 256 + threadIdx.x;
  int n = gid >> 3, q = gid & 7;
  if (n >= NN) return;
  float4 mu, rs, be;
  if (BN) {
    mu = *(const float4*)&bnp[q * 4];
    rs = *(const float4*)&bnp[DD + q * 4];
    be = *(const float4*)&bnp[2 * DD + q * 4];
  }
  int beg = rowstart[n], end = rowstart[n + 1];
  float4 a0 = make_float4(0.f, 0.f, 0.f, 0.f);
  float4 a1 = a0, a2 = a0, a3 = a0;
  int i = beg;
  for (; i + 4 <= end; i += 4) {
    int s0 = srcidx[i], s1 = srcidx[i + 1], s2 = srcidx[i + 2], s3 = srcidx[i + 3];
    float4 v0 = *(const float4*)&src[(size_t)s0 * DD + q * 4];
    float4 v1 = *(const float4*)&src[(size_t)s1 * DD + q * 4];
    float4 v2 = *(const float4*)&src[(size_t)s2 * DD + q * 4];
    float4 v3 = *(const float4*)&src[(size_t)s3 * DD + q * 4];
    if (BN) {
      v0 = make_float4((v0.x - mu.x) * rs.x + be.x, (v0.y - mu.y) * rs.y + be.y,
                       (v0.z - mu.z) * rs.z + be.z, (v0.w - mu.w) * rs.w + be.w);
      v1 = make_float4((v1.x - mu.x) * rs.x + be.x, (v1.y - mu.y) * rs.y + be.y,
                       (v1.z - mu.z) * rs.z + be.z, (v1.w - mu.w) * rs.w + be.w);
      v2 = make_float4((v2.x - mu.x) * rs.x + be.x, (v2.y - mu.y) * rs.y + be.y,
                       (v2.z - mu.z) * rs.z + be.z, (v2.w - mu.w) * rs.w + be.w);
      v3 = make_float4((v3.x - mu.x) * rs.x + be.x, (v3.y - mu.y) * rs.y + be.y,
                       (v3.z - mu.z) * rs.z + be.z, (v3.w - mu.w) * rs.w + be.w);
    }
    a0.x += v0.x; a0.y += v0.y; a0.z += v0.z; a0.w += v0.w;
    a1.x += v1.x; a1.y += v1.y; a1.z += v1.z; a1.w += v1.w;
    a2.x += v2.x; a2.y += v2.y; a2.z += v2.z; a2.w += v2.w;
    a3.x += v3.x; a3.y += v3.y; a3.z += v3.z; a3.w += v3.w;
  }
  for (; i < end; ++i) {
    int s0 = srcidx[i];
    float4 v0 = *(const float4*)&src[(size_t)s0 * DD + q * 4];
    if (BN)
      v0 = make_float4((v0.x - mu.x) * rs.x + be.x, (v0.y - mu.y) * rs.y + be.y,
                       (v0.z - mu.z) * rs.z + be.z, (v0.w - mu.w) * rs.w + be.w);
    a0.x += v0.x; a0.y += v0.y; a0.z += v0.z; a0.w += v0.w;
  }
  float4 r = make_float4(a0.x + a1.x + a2.x + a3.x, a0.y + a1.y + a2.y + a3.y,
                         a0.z + a1.z + a2.z + a3.z, a0.w + a1.w + a2.w + a3.w);
  *(float4*)&agg[(size_t)n * DD + q * 4] = r;
}

// ---------------- K1 v4: z = x @ Mp + cvec (unchanged this round)
__global__ __launch_bounds__(256) void k1_lin1(
    const float* __restrict__ x, const float* __restrict__ Mp,
    const float* __restrict__ cvec, float* __restrict__ z) {
  __shared__ float xs[2][K1CH][132];
  __shared__ float ms[2][K1CH][36];
  const int tid = threadIdx.x;
  const int wave = tid >> 6, lane = tid & 63;
  const int q8 = wave * 8;
  const int row0 = blockIdx.x * 128;
  const int ra = tid >> 2, ka = (tid & 3) * 4;
  const int rb = ra + 64, kb = ka;
  const int gra = row0 + ra, grb = row0 + rb;
  const int mk = tid >> 3, mj = (tid & 7) * 4;

  float acc0[8] = {}, acc1[8] = {};
  float4 pa, pb, pm;

  pa = make_float4(0.f, 0.f, 0.f, 0.f);
  pb = pa;
  if (gra < NN) pa = *(const float4*)&x[(size_t)gra * FI + ka];
  if (grb < NN) pb = *(const float4*)&x[(size_t)grb * FI + kb];
  if (tid < 128) pm = *(const float4*)&Mp[mk * DD + mj];
  {
    xs[0][ka + 0][ra] = pa.x; xs[0][ka + 1][ra] = pa.y;
    xs[0][ka + 2][ra] = pa.z; xs[0][ka + 3][ra] = pa.w;
    xs[0][kb + 0][rb] = pb.x; xs[0][kb + 1][rb] = pb.y;
    xs[0][kb + 2][rb] = pb.z; xs[0][kb + 3][rb] = pb.w;
    if (tid < 128) *(float4*)&ms[0][mk][mj] = pm;
  }

  int cur = 0;
  for (int c = 0; c < K1NCH; ++c) {
    if (c + 1 < K1NCH) {
      const int kbase = (c + 1) * K1CH;
      pa = make_float4(0.f, 0.f, 0.f, 0.f);
      pb = pa;
      int gk = kbase + ka;
      if (gra < NN) {
        if (gk + 3 < FI) {
          pa = *(const float4*)&x[(size_t)gra * FI + gk];
        } else {
          if (gk + 0 < FI) pa.x = x[(size_t)gra * FI + gk + 0];
          if (gk + 1 < FI) pa.y = x[(size_t)gra * FI + gk + 1];
          if (gk + 2 < FI) pa.z = x[(size_t)gra * FI + gk + 2];
        }
      }
      if (grb < NN) {
        if (gk + 3 < FI) {
          pb = *(const float4*)&x[(size_t)grb * FI + gk];
        } else {
          if (gk + 0 < FI) pb.x = x[(size_t)grb * FI + gk + 0];
          if (gk + 1 < FI) pb.y = x[(size_t)grb * FI + gk + 1];
          if (gk + 2 < FI) pb.z = x[(size_t)grb * FI + gk + 2];
        }
      }
      if (tid < 128) pm = *(const float4*)&Mp[(kbase + mk) * DD + mj];
    }
    __syncthreads();
    #pragma unroll
    for (int kk = 0; kk < K1CH; ++kk) {
      float x0 = xs[cur][kk][lane];
      float x1 = xs[cur][kk][64 + lane];
      float4 m0 = *(const float4*)&ms[cur][kk][q8];
      float4 m1 = *(const float4*)&ms[cur][kk][q8 + 4];
      acc0[0] = fmaf(x0, m0.x, acc0[0]); acc1[0] = fmaf(x1, m0.x, acc1[0]);
      acc0[1] = fmaf(x0, m0.y, acc0[1]); acc1[1] = fmaf(x1, m0.y, acc1[1]);
      acc0[2] = fmaf(x0, m0.z, acc0[2]); acc1[2] = fmaf(x1, m0.z, acc1[2]);
      acc0[3] = fmaf(x0, m0.w, acc0[3]); acc1[3] = fmaf(x1, m0.w, acc1[3]);
      acc0[4] = fmaf(x0, m1.x, acc0[4]); acc1[4] = fmaf(x1, m1.x, acc1[4]);
      acc0[5] = fmaf(x0, m1.y, acc0[5]); acc1[5] = fmaf(x1, m1.y, acc1[5]);
      acc0[6] = fmaf(x0, m1.z, acc0[6]); acc1[6] = fmaf(x1, m1.z, acc1[6]);
      acc0[7] = fmaf(x0, m1.w, acc0[7]); acc1[7] = fmaf(x1, m1.w, acc1[7]);
    }
    if (c + 1 < K1NCH) {
      int nxt = cur ^ 1;
      xs[nxt][ka + 0][ra] = pa.x; xs[nxt][ka + 1][ra] = pa.y;
      xs[nxt][ka + 2][ra] = pa.z; xs[nxt][ka + 3][ra] = pa.w;
      xs[nxt][kb + 0][rb] = pb.x; xs[nxt][kb + 1][rb] = pb.y;
      xs[nxt][kb + 2][rb] = pb.z; xs[nxt][kb + 3][rb] = pb.w;
      if (tid < 128) *(float4*)&ms[nxt][mk][mj] = pm;
    }
    cur ^= 1;
  }

  const float4 cv0 = *(const float4*)&cvec[q8];
  const float4 cv1 = *(const float4*)&cvec[q8 + 4];
  int rowA = row0 + lane, rowB = row0 + 64 + lane;
  if (rowA < NN) {
    float* zp = &z[(size_t)rowA * DD + q8];
    *(float4*)&zp[0] = make_float4(acc0[0] + cv0.x, acc0[1] + cv0.y, acc0[2] + cv0.z, acc0[3] + cv0.w);
    *(float4*)&zp[4] = make_float4(acc0[4] + cv1.x, acc0[5] + cv1.y, acc0[6] + cv1.z, acc0[7] + cv1.w);
  }
  if (rowB < NN) {
    float* zp = &z[(size_t)rowB * DD + q8];
    *(float4*)&zp[0] = make_float4(acc1[0] + cv0.x, acc1[1] + cv0.y, acc1[2] + cv0.z, acc1[3] + cv0.w);
    *(float4*)&zp[4] = make_float4(acc1[4] + cv1.x, acc1[5] + cv1.y, acc1[6] + cv1.z, acc1[7] + cv1.w);
  }
}

// ---------------- K3: g1 = relu(z+agg+b1) @ w2 + b2 ; stats
__global__ __launch_bounds__(256) void k3_mlp1(
    const float* __restrict__ z, const float* __restrict__ agg,
    const float* __restrict__ w2, const float* __restrict__ b1, const float* __restrict__ b2,
    float* __restrict__ g1, float* __restrict__ stats) {
  __shared__ float us[256][DD + 1];
  __shared__ float w2s[DD][DD];
  __shared__ float ps[4][2 * DD];
  const int tid = threadIdx.x;
  const int n0 = blockIdx.x * 256;
  for (int i = tid; i < DD * DD; i += 256) w2s[i >> 5][i & 31] = w2[i];
  #pragma unroll
  for (int i = 0; i < 32; ++i) {
    int l = tid + i * 256;
    int r = l >> 5, c = l & 31;
    float v = 0.f;
    if (n0 + r < NN) {
      size_t gi = (size_t)(n0 + r) * DD + c;
      v = z[gi] + agg[gi];
    }
    us[r][c] = v;
  }
  __syncthreads();
  float t[DD];
  #pragma unroll
  for (int k = 0; k < DD; ++k) t[k] = fmaxf(us[tid][k] + b1[k], 0.f);
  float g[DD];
  #pragma unroll
  for (int j = 0; j < DD; ++j) g[j] = b2[j];
  #pragma unroll
  for (int k = 0; k < DD; ++k) {
    float tv = t[k];
    #pragma unroll
    for (int j = 0; j < DD; ++j) g[j] = fmaf(tv, w2s[k][j], g[j]);
  }
  bool valid = (n0 + tid) < NN;
  #pragma unroll
  for (int j = 0; j < DD; ++j) us[tid][j] = g[j];
  int wave = tid >> 6, lane = tid & 63;
  #pragma unroll
  for (int j = 0; j < DD; ++j) {
    float v = valid ? g[j] : 0.f;
    float qq = v * v;
    #pragma unroll
    for (int off = 1; off < 64; off <<= 1) { v += __shfl_xor(v, off); qq += __shfl_xor(qq, off); }
    if (lane == 0) { ps[wave][j] = v; ps[wave][DD + j] = qq; }
  }
  __syncthreads();
  if (tid < 2 * DD)
    atomAdd(&stats[tid], ps[0][tid] + ps[1][tid] + ps[2][tid] + ps[3][tid]);
  #pragma unroll
  for (int i = 0; i < 32; ++i) {
    int l = tid + i * 256;
    int r = l >> 5, c = l & 31;
    if (n0 + r < NN) g1[(size_t)(n0 + r) * DD + c] = us[r][c];
  }
}

// ---------------- K3b: finalize BN1 params
__global__ void k3b_bn(const float* __restrict__ stats, const float* __restrict__ gamma,
                       const float* __restrict__ beta, float* __restrict__ bnp) {
  int t = threadIdx.x;
  if (t < DD) {
    float mu = stats[t] * (1.f / NN);
    float var = stats[DD + t] * (1.f / NN) - mu * mu;
    bnp[t] = mu;
    bnp[DD + t] = rsqrtf(var + BN_EPS) * gamma[t];
    bnp[2 * DD + t] = beta[t];
  }
}

// ---------------- K6: g2 = relu((bn1(g1)+agg2)@w1+b1)@w2+b2 ; stats2
__global__ __launch_bounds__(256) void k6_mlp2(
    const float* __restrict__ g1, const float* __restrict__ agg,
    const float* __restrict__ bnp,
    const float* __restrict__ w1, const float* __restrict__ b1,
    const float* __restrict__ w2, const float* __restrict__ b2,
    float* __restrict__ g2, float* __restrict__ stats) {
  __shared__ float us[256][DD + 1];
  __shared__ float w1s[DD][DD];
  __shared__ float w2s[DD][DD];
  __shared__ float ps[4][2 * DD];
  const int tid = threadIdx.x;
  const int n0 = blockIdx.x * 256;
  for (int i = tid; i < DD * DD; i += 256) { w1s[i >> 5][i & 31] = w1[i]; w2s[i >> 5][i & 31] = w2[i]; }
  #pragma unroll
  for (int i = 0; i < 32; ++i) {
    int l = tid + i * 256;
    int r = l >> 5, c = l & 31;
    float v = 0.f;
    if (n0 + r < NN) {
      size_t gi = (size_t)(n0 + r) * DD + c;
      v = (g1[gi] - bnp[c]) * bnp[DD + c] + bnp[2 * DD + c] + agg[gi];
    }
    us[r][c] = v;
  }
  __syncthreads();
  float t1[DD];
  #pragma unroll
  for (int j = 0; j < DD; ++j) t1[j] = b1[j];
  #pragma unroll
  for (int k = 0; k < DD; ++k) {
    float uv = us[tid][k];
    #pragma unroll
    for (int j = 0; j < DD; ++j) t1[j] = fmaf(uv, w1s[k][j], t1[j]);
  }
  #pragma unroll
  for (int j = 0; j < DD; ++j) t1[j] = fmaxf(t1[j], 0.f);
  float g[DD];
  #pragma unroll
  for (int j = 0; j < DD; ++j) g[j] = b2[j];
  #pragma unroll
  for (int k = 0; k < DD; ++k) {
    float tv = t1[k];
    #pragma unroll
    for (int j = 0; j < DD; ++j) g[j] = fmaf(tv, w2s[k][j], g[j]);
  }
  bool valid = (n0 + tid) < NN;
  #pragma unroll
  for (int j = 0; j < DD; ++j) us[tid][j] = g[j];
  int wave = tid >> 6, lane = tid & 63;
  #pragma unroll
  for (int j = 0; j < DD; ++j) {
    float v = valid ? g[j] : 0.f;
    float qq = v * v;
    #pragma unroll
    for (int off = 1; off < 64; off <<= 1) { v += __shfl_xor(v, off); qq += __shfl_xor(qq, off); }
    if (lane == 0) { ps[wave][j] = v; ps[wave][DD + j] = qq; }
  }
  __syncthreads();
  if (tid < 2 * DD)
    atomAdd(&stats[tid], ps[0][tid] + ps[1][tid] + ps[2][tid] + ps[3][tid]);
  #pragma unroll
  for (int i = 0; i < 32; ++i) {
    int l = tid + i * 256;
    int r = l >> 5, c = l & 31;
    if (n0 + r < NN) g2[(size_t)(n0 + r) * DD + c] = us[r][c];
  }
}

// ---------------- K7: out = relu(bn2(g2)@fc1+b)@fc2+b
__global__ __launch_bounds__(256) void k7_head(
    const float* __restrict__ g2, const float* __restrict__ stats2,
    const float* __restrict__ bn2_g, const float* __restrict__ bn2_b,
    const float* __restrict__ fc1_w, const float* __restrict__ fc1_b,
    const float* __restrict__ fc2_w, const float* __restrict__ fc2_b,
    float* __restrict__ out) {
  __shared__ float buf[256 * 42];
  __shared__ float fc1s[DD * DD];
  __shared__ float fc2s[DD * CC];
  __shared__ float mu2[DD], rsg2[DD], bet2[DD];
  const int tid = threadIdx.x;
  const int n0 = blockIdx.x * 256;
  if (tid < DD) {
    float mu = stats2[tid] * (1.f / NN);
    float var = stats2[DD + tid] * (1.f / NN) - mu * mu;
    mu2[tid] = mu;
    rsg2[tid] = rsqrtf(var + BN_EPS) * bn2_g[tid];
    bet2[tid] = bn2_b[tid];
  }
  for (int i = tid; i < DD * DD; i += 256) fc1s[i] = fc1_w[i];
  for (int i = tid; i < DD * CC; i += 256) fc2s[i] = fc2_w[i];
  __syncthreads();
  #pragma unroll
  for (int i = 0; i < 32; ++i) {
    int l = tid + i * 256;
    int r = l >> 5, c = l & 31;
    float v = 0.f;
    if (n0 + r < NN) v = (g2[(size_t)(n0 + r) * DD + c] - mu2[c]) * rsg2[c] + bet2[c];
    buf[r * 33 + c] = v;
  }
  __syncthreads();
  float t[DD];
  #pragma unroll
  for (int j = 0; j < DD; ++j) t[j] = fc1_b[j];
  #pragma unroll
  for (int k = 0; k < DD; ++k) {
    float uv = buf[tid * 33 + k];
    #pragma unroll
    for (int j = 0; j < DD; ++j) t[j] = fmaf(uv, fc1s[k * DD + j], t[j]);
  }
  #pragma unroll
  for (int j = 0; j < DD; ++j) t[j] = fmaxf(t[j], 0.f);
  float o[CC];
  #pragma unroll
  for (int j = 0; j < CC; ++j) o[j] = fc2_b[j];
  #pragma unroll
  for (int k = 0; k < DD; ++k) {
    float tv = t[k];
    #pragma unroll
    for (int j = 0; j < CC; ++j) o[j] = fmaf(tv, fc2s[k * CC + j], o[j]);
  }
  __syncthreads();
  #pragma unroll
  for (int j = 0; j < CC; ++j) buf[tid * 42 + j] = o[j];
  __syncthreads();
  for (int i = 0; i < CC; ++i) {
    int l = tid + i * 256;
    int r = l / CC, c = l % CC;
    if (n0 + r < NN) out[(size_t)(n0 + r) * CC + c] = buf[r * 42 + c];
  }
}

extern "C" void kernel_launch(void* const* d_in, const int* in_sizes, int n_in,
                              void* d_out, int out_size, void* d_ws, size_t ws_size,
                              hipStream_t stream) {
  const float* x      = (const float*)d_in[0];
  const int*   ei     = (const int*)d_in[1];
  const float* lin1_w = (const float*)d_in[2];
  const float* lin1_b = (const float*)d_in[3];
  const float* nn1_w1 = (const float*)d_in[4];
  const float* nn1_b1 = (const float*)d_in[5];
  const float* nn1_w2 = (const float*)d_in[6];
  const float* nn1_b2 = (const float*)d_in[7];
  const float* bn1_g  = (const float*)d_in[8];
  const float* bn1_b  = (const float*)d_in[9];
  const float* nn2_w1 = (const float*)d_in[10];
  const float* nn2_b1 = (const float*)d_in[11];
  const float* nn2_w2 = (const float*)d_in[12];
  const float* nn2_b2 = (const float*)d_in[13];
  const float* bn2_g  = (const float*)d_in[14];
  const float* bn2_b  = (const float*)d_in[15];
  const float* fc1_w  = (const float*)d_in[16];
  const float* fc1_b  = (const float*)d_in[17];
  const float* fc2_w  = (const float*)d_in[18];
  const float* fc2_b  = (const float*)d_in[19];
  float* out = (float*)d_out;

  float* ws = (float*)d_ws;
  size_t nd = (size_t)NN * DD;
  float* A      = ws;            // z
  float* B      = ws + nd;       // agg1, then agg2
  float* Cb     = ws + 2 * nd;   // g1, then g2
  float* Mp     = ws + 3 * nd;   // 640*32 (padded)
  float* cvec   = Mp + FIP * DD;
  float* stats1 = cvec + 32;
  float* bnp1   = stats1 + 64;
  float* stats2 = bnp1 + 96;
  int*   rowstart = (int*)(stats2 + 64);               // NN+1
  int*   srcidx   = rowstart + (NN + 1);               // NE
  int*   tsrc     = srcidx + NE;                       // NE
  unsigned char* tdst = (unsigned char*)(tsrc + NE);   // NE bytes (NE%4==0)
  int*   bcount   = (int*)(tdst + NE);                 // NB
  int*   bcursor  = bcount + NB;                       // NB
  int*   bbase    = bcursor + NB;                      // NB+1

  // bucketed CSR build
  hipMemsetAsync(bcount, 0, NB * sizeof(int), stream);
  kb_hist<<<SCB, 256, 0, stream>>>(ei, bcount);
  kb_scan<<<1, 512, 0, stream>>>(bcount, bbase, bcursor, rowstart);
  kb_scatter<<<SCB, 256, 0, stream>>>(ei, bcursor, tsrc, tdst);
  kb_fine<<<NB, 256, 0, stream>>>(bbase, tsrc, tdst, rowstart, srcidx);

  k0_prep<<<(FIP * DD + 255) / 256, 256, 0, stream>>>(lin1_w, lin1_b, nn1_w1, Mp, cvec, stats1, stats2);
  k1_lin1<<<(NN + 127) / 128, 256, 0, stream>>>(x, Mp, cvec, A);
  k_gather_t<false><<<(NN * 8 + 255) / 256, 256, 0, stream>>>(rowstart, srcidx, A, nullptr, B);
  k3_mlp1<<<(NN + 255) / 256, 256, 0, stream>>>(A, B, nn1_w2, nn1_b1, nn1_b2, Cb, stats1);
  k3b_bn<<<1, 64, 0, stream>>>(stats1, bn1_g, bn1_b, bnp1);
  k_gather_t<true><<<(NN * 8 + 255) / 256, 256, 0, stream>>>(rowstart, srcidx, Cb, bnp1, B);
  k6_mlp2<<<(NN + 255) / 256, 256, 0, stream>>>(Cb, B, bnp1, nn2_w1, nn2_b1, nn2_w2, nn2_b2, A, stats2);
  k7_head<<<(NN + 255) / 256, 256, 0, stream>>>(A, stats2, bn2_g, bn2_b, fc1_w, fc1_b, fc2_w, fc2_b, out);
}

// Round 8
// 340.239 us; speedup vs baseline: 1.4010x; 1.0656x over previous
//
#include <hip/hip_runtime.h>
#include <cstdint>

#define NN 100000
#define NE 1600000
#define FI 602
#define DD 32
#define CC 41
#define BN_EPS 1e-5f
#define KSTEPS 19                 // 19*32 = 608 >= 602 (k-padded with zeros)

// bucketed CSR build
#define NPB 256                   // nodes per bucket (dst >> 8)
#define NB 391                    // ceil(NN/NPB)
#define EPT 13                    // edges per thread in hist/scatter
#define SCB 481                   // ceil(NE / (256*EPT))

typedef __attribute__((ext_vector_type(8))) short bf16x8;
typedef __attribute__((ext_vector_type(4))) float f32x4;

__device__ __forceinline__ void atomAdd(float* p, float v) {
#ifdef __HIP_PLATFORM_AMD__
  unsafeAtomicAdd(p, v);
#else
  atomicAdd(p, v);
#endif
}

// ---------------- K0: M = lin1_w @ nn1_w1, emitted directly as MFMA B-fragments
// (bf16 hi/lo split), laid out [step][colhalf][lane][j] so k1 loads one bf16x8
// per fragment. Also cvec = lin1_b @ nn1_w1 ; zero stats.
__global__ __launch_bounds__(256) void k0_prep(
    const float* __restrict__ lin1_w, const float* __restrict__ lin1_b,
    const float* __restrict__ nn1_w1,
    unsigned short* __restrict__ Bhi, unsigned short* __restrict__ Blo,
    float* __restrict__ cvec,
    float* __restrict__ stats1, float* __restrict__ stats2) {
  int o = blockIdx.x * 256 + threadIdx.x;   // over 608*32
  if (o < KSTEPS * 32 * 32) {
    int k = o >> 5, j = o & 31;
    float s = 0.f;
    if (k < FI) {
      #pragma unroll 4
      for (int c = 0; c < 2 * DD; ++c) s = fmaf(lin1_w[k * (2 * DD) + c], nn1_w1[c * DD + j], s);
    }
    // fragment position: step st, k-group g (8 k's), slot jj, col-half h, lane
    int st = k >> 5, kk = k & 31, g = kk >> 3, jj = kk & 7;
    int h = j >> 4, lane = g * 16 + (j & 15);
    int idx = ((st * 2 + h) * 64 + lane) * 8 + jj;
    unsigned ub = __float_as_uint(s);
    unsigned short hi = (unsigned short)(ub >> 16);
    float hv = __uint_as_float((unsigned)hi << 16);
    float d = s - hv;
    Bhi[idx] = hi;
    Blo[idx] = (unsigned short)(__float_as_uint(d) >> 16);
  }
  if (blockIdx.x == 0) {
    int t = threadIdx.x;
    if (t < DD) {
      float s = 0.f;
      for (int c = 0; c < 2 * DD; ++c) s = fmaf(lin1_b[c], nn1_w1[c * DD + t], s);
      cvec[t] = s;
    }
    if (t >= 128 && t < 192) stats1[t - 128] = 0.f;
    if (t >= 192) stats2[t - 192] = 0.f;
  }
}

// ---------------- bucketed CSR build ----------------
__global__ __launch_bounds__(256) void kb_hist(const int* __restrict__ ei, int* __restrict__ bcount) {
  __shared__ int h[NB];
  const int t = threadIdx.x;
  for (int i = t; i < NB; i += 256) h[i] = 0;
  __syncthreads();
  const int base = blockIdx.x * (256 * EPT);
  #pragma unroll
  for (int i = 0; i < EPT; ++i) {
    int e = base + i * 256 + t;
    if (e < NE) atomicAdd(&h[ei[NE + e] >> 8], 1);
  }
  __syncthreads();
  for (int i = t; i < NB; i += 256) if (h[i]) atomicAdd(&bcount[i], h[i]);
}

__global__ __launch_bounds__(512) void kb_scan(const int* __restrict__ bcount,
                                               int* __restrict__ bbase,
                                               int* __restrict__ bcursor,
                                               int* __restrict__ rowstart) {
  __shared__ int ps[512];
  const int t = threadIdx.x;
  int v = (t < NB) ? bcount[t] : 0;
  ps[t] = v;
  __syncthreads();
  #pragma unroll
  for (int off = 1; off < 512; off <<= 1) {
    int u = (t >= off) ? ps[t - off] : 0;
    __syncthreads();
    ps[t] += u;
    __syncthreads();
  }
  int excl = ps[t] - v;
  if (t < NB) { bbase[t] = excl; bcursor[t] = excl; }
  if (t == 0) { bbase[NB] = NE; rowstart[NN] = NE; }
}

__global__ __launch_bounds__(256) void kb_scatter(const int* __restrict__ ei,
                                                  int* __restrict__ bcursor,
                                                  int* __restrict__ tsrc,
                                                  unsigned char* __restrict__ tdst) {
  __shared__ int cnt[NB];
  __shared__ int wbase[NB];
  const int t = threadIdx.x;
  for (int i = t; i < NB; i += 256) cnt[i] = 0;
  __syncthreads();
  const int base = blockIdx.x * (256 * EPT);
  int s[EPT], d[EPT];
  #pragma unroll
  for (int i = 0; i < EPT; ++i) {
    int e = base + i * 256 + t;
    if (e < NE) {
      s[i] = ei[e];
      d[i] = ei[NE + e];
      atomicAdd(&cnt[d[i] >> 8], 1);
    } else {
      s[i] = -1; d[i] = -1;
    }
  }
  __syncthreads();
  for (int i = t; i < NB; i += 256) wbase[i] = atomicAdd(&bcursor[i], cnt[i]);
  __syncthreads();
  #pragma unroll
  for (int i = 0; i < EPT; ++i) {
    if (d[i] >= 0) {
      int p = atomicAdd(&wbase[d[i] >> 8], 1);
      tsrc[p] = s[i];
      tdst[p] = (unsigned char)(d[i] & (NPB - 1));
    }
  }
}

__global__ __launch_bounds__(256) void kb_fine(const int* __restrict__ bbase,
                                               const int* __restrict__ tsrc,
                                               const unsigned char* __restrict__ tdst,
                                               int* __restrict__ rowstart,
                                               int* __restrict__ srcidx) {
  __shared__ int deg[NPB];
  __shared__ int cur[NPB];
  __shared__ int woff[4];
  const int b = blockIdx.x, t = threadIdx.x;
  const int beg = bbase[b], end = bbase[b + 1];
  deg[t] = 0;
  __syncthreads();
  for (int i = beg + t; i < end; i += 256) atomicAdd(&deg[tdst[i]], 1);
  __syncthreads();
  int v = deg[t];
  int lane = t & 63, wave = t >> 6;
  int inc = v;
  #pragma unroll
  for (int off = 1; off < 64; off <<= 1) {
    int u = __shfl_up(inc, off);
    if (lane >= off) inc += u;
  }
  if (lane == 63) woff[wave] = inc;
  __syncthreads();
  int wadd = 0;
  for (int w = 0; w < wave; ++w) wadd += woff[w];
  int excl = wadd + inc - v;
  int gnode = b * NPB + t;
  if (gnode < NN) rowstart[gnode] = beg + excl;
  cur[t] = beg + excl;
  __syncthreads();
  for (int i = beg + t; i < end; i += 256) {
    int p = atomicAdd(&cur[tdst[i]], 1);
    srcidx[p] = tsrc[i];
  }
}

// ---------------- gather (optionally fused BN on the gathered operand)
template <bool BN>
__global__ __launch_bounds__(256) void k_gather_t(const int* __restrict__ rowstart,
                                                  const int* __restrict__ srcidx,
                                                  const float* __restrict__ src,
                                                  const float* __restrict__ bnp,
                                                  float* __restrict__ agg) {
  int gid = blockIdx.x * 256 + threadIdx.x;
  int n = gid >> 3, q = gid & 7;
  if (n >= NN) return;
  float4 mu, rs, be;
  if (BN) {
    mu = *(const float4*)&bnp[q * 4];
    rs = *(const float4*)&bnp[DD + q * 4];
    be = *(const float4*)&bnp[2 * DD + q * 4];
  }
  int beg = rowstart[n], end = rowstart[n + 1];
  float4 a0 = make_float4(0.f, 0.f, 0.f, 0.f);
  float4 a1 = a0, a2 = a0, a3 = a0;
  int i = beg;
  for (; i + 4 <= end; i += 4) {
    int s0 = srcidx[i], s1 = srcidx[i + 1], s2 = srcidx[i + 2], s3 = srcidx[i + 3];
    float4 v0 = *(const float4*)&src[(size_t)s0 * DD + q * 4];
    float4 v1 = *(const float4*)&src[(size_t)s1 * DD + q * 4];
    float4 v2 = *(const float4*)&src[(size_t)s2 * DD + q * 4];
    float4 v3 = *(const float4*)&src[(size_t)s3 * DD + q * 4];
    if (BN) {
      v0 = make_float4((v0.x - mu.x) * rs.x + be.x, (v0.y - mu.y) * rs.y + be.y,
                       (v0.z - mu.z) * rs.z + be.z, (v0.w - mu.w) * rs.w + be.w);
      v1 = make_float4((v1.x - mu.x) * rs.x + be.x, (v1.y - mu.y) * rs.y + be.y,
                       (v1.z - mu.z) * rs.z + be.z, (v1.w - mu.w) * rs.w + be.w);
      v2 = make_float4((v2.x - mu.x) * rs.x + be.x, (v2.y - mu.y) * rs.y + be.y,
                       (v2.z - mu.z) * rs.z + be.z, (v2.w - mu.w) * rs.w + be.w);
      v3 = make_float4((v3.x - mu.x) * rs.x + be.x, (v3.y - mu.y) * rs.y + be.y,
                       (v3.z - mu.z) * rs.z + be.z, (v3.w - mu.w) * rs.w + be.w);
    }
    a0.x += v0.x; a0.y += v0.y; a0.z += v0.z; a0.w += v0.w;
    a1.x += v1.x; a1.y += v1.y; a1.z += v1.z; a1.w += v1.w;
    a2.x += v2.x; a2.y += v2.y; a2.z += v2.z; a2.w += v2.w;
    a3.x += v3.x; a3.y += v3.y; a3.z += v3.z; a3.w += v3.w;
  }
  for (; i < end; ++i) {
    int s0 = srcidx[i];
    float4 v0 = *(const float4*)&src[(size_t)s0 * DD + q * 4];
    if (BN)
      v0 = make_float4((v0.x - mu.x) * rs.x + be.x, (v0.y - mu.y) * rs.y + be.y,
                       (v0.z - mu.z) * rs.z + be.z, (v0.w - mu.w) * rs.w + be.w);
    a0.x += v0.x; a0.y += v0.y; a0.z += v0.z; a0.w += v0.w;
  }
  float4 r = make_float4(a0.x + a1.x + a2.x + a3.x, a0.y + a1.y + a2.y + a3.y,
                         a0.z + a1.z + a2.z + a3.z, a0.w + a1.w + a2.w + a3.w);
  *(float4*)&agg[(size_t)n * DD + q * 4] = r;
}

// ---------------- K1 v5 (MFMA): z = x @ M + cvec via split-bf16 hi/lo.
// One wave per 16 rows (6250 waves). No LDS, no barriers. Per k-step (K=32):
// 2 float4 x-loads, hi/lo split, 4 B-fragment loads (L2-resident), 6 MFMAs.
// z = ahi@Mhi + alo@Mhi + ahi@Mlo  (lo*lo dropped, ~2^-17 relative).
__global__ __launch_bounds__(256) void k1_mfma(
    const float* __restrict__ x,
    const unsigned short* __restrict__ Bhi, const unsigned short* __restrict__ Blo,
    const float* __restrict__ cvec, float* __restrict__ z) {
  const int lane = threadIdx.x & 63;
  const int wid = (blockIdx.x * 256 + threadIdx.x) >> 6;
  const int row0 = wid * 16;
  if (row0 >= NN) return;
  const int g = lane >> 4;                 // k-group (8 k's per group)
  const int r = row0 + (lane & 15);        // A-fragment row
  const float* __restrict__ xr = x + (size_t)r * FI;
  f32x4 acc0 = {0.f, 0.f, 0.f, 0.f};
  f32x4 acc1 = {0.f, 0.f, 0.f, 0.f};
  for (int s = 0; s < KSTEPS; ++s) {
    const int k0 = s * 32 + g * 8;
    float xv[8];
    if (k0 + 8 <= FI) {
      float4 a = *(const float4*)&xr[k0];
      float4 b = *(const float4*)&xr[k0 + 4];
      xv[0] = a.x; xv[1] = a.y; xv[2] = a.z; xv[3] = a.w;
      xv[4] = b.x; xv[5] = b.y; xv[6] = b.z; xv[7] = b.w;
    } else {
      #pragma unroll
      for (int j = 0; j < 8; ++j) xv[j] = (k0 + j < FI) ? xr[k0 + j] : 0.f;
    }
    bf16x8 ahi, alo;
    #pragma unroll
    for (int j = 0; j < 8; ++j) {
      unsigned ub = __float_as_uint(xv[j]);
      unsigned short h = (unsigned short)(ub >> 16);
      float hv = __uint_as_float((unsigned)h << 16);
      float d = xv[j] - hv;
      ahi[j] = (short)h;
      alo[j] = (short)(__float_as_uint(d) >> 16);
    }
    const size_t fb = ((size_t)(s * 2) * 64 + lane) * 8;
    bf16x8 bh0 = *(const bf16x8*)&Bhi[fb];
    bf16x8 bl0 = *(const bf16x8*)&Blo[fb];
    bf16x8 bh1 = *(const bf16x8*)&Bhi[fb + 512];
    bf16x8 bl1 = *(const bf16x8*)&Blo[fb + 512];
    acc0 = __builtin_amdgcn_mfma_f32_16x16x32_bf16(ahi, bh0, acc0, 0, 0, 0);
    acc1 = __builtin_amdgcn_mfma_f32_16x16x32_bf16(ahi, bh1, acc1, 0, 0, 0);
    acc0 = __builtin_amdgcn_mfma_f32_16x16x32_bf16(alo, bh0, acc0, 0, 0, 0);
    acc1 = __builtin_amdgcn_mfma_f32_16x16x32_bf16(alo, bh1, acc1, 0, 0, 0);
    acc0 = __builtin_amdgcn_mfma_f32_16x16x32_bf16(ahi, bl0, acc0, 0, 0, 0);
    acc1 = __builtin_amdgcn_mfma_f32_16x16x32_bf16(ahi, bl1, acc1, 0, 0, 0);
  }
  // C/D layout (HW-verified): col = lane&15, row = (lane>>4)*4 + reg
  const int c0 = lane & 15;
  const float cva = cvec[c0], cvb = cvec[16 + c0];
  #pragma unroll
  for (int j = 0; j < 4; ++j) {
    int rr = row0 + g * 4 + j;
    z[(size_t)rr * DD + c0] = acc0[j] + cva;
    z[(size_t)rr * DD + 16 + c0] = acc1[j] + cvb;
  }
}

// ---------------- K3: g1 = relu(z+agg+b1) @ w2 + b2 ; stats
__global__ __launch_bounds__(256) void k3_mlp1(
    const float* __restrict__ z, const float* __restrict__ agg,
    const float* __restrict__ w2, const float* __restrict__ b1, const float* __restrict__ b2,
    float* __restrict__ g1, float* __restrict__ stats) {
  __shared__ float us[256][DD + 1];
  __shared__ float w2s[DD][DD];
  __shared__ float ps[4][2 * DD];
  const int tid = threadIdx.x;
  const int n0 = blockIdx.x * 256;
  for (int i = tid; i < DD * DD; i += 256) w2s[i >> 5][i & 31] = w2[i];
  #pragma unroll
  for (int i = 0; i < 32; ++i) {
    int l = tid + i * 256;
    int r = l >> 5, c = l & 31;
    float v = 0.f;
    if (n0 + r < NN) {
      size_t gi = (size_t)(n0 + r) * DD + c;
      v = z[gi] + agg[gi];
    }
    us[r][c] = v;
  }
  __syncthreads();
  float t[DD];
  #pragma unroll
  for (int k = 0; k < DD; ++k) t[k] = fmaxf(us[tid][k] + b1[k], 0.f);
  float g[DD];
  #pragma unroll
  for (int j = 0; j < DD; ++j) g[j] = b2[j];
  #pragma unroll
  for (int k = 0; k < DD; ++k) {
    float tv = t[k];
    #pragma unroll
    for (int j = 0; j < DD; ++j) g[j] = fmaf(tv, w2s[k][j], g[j]);
  }
  bool valid = (n0 + tid) < NN;
  #pragma unroll
  for (int j = 0; j < DD; ++j) us[tid][j] = g[j];
  int wave = tid >> 6, lane = tid & 63;
  #pragma unroll
  for (int j = 0; j < DD; ++j) {
    float v = valid ? g[j] : 0.f;
    float qq = v * v;
    #pragma unroll
    for (int off = 1; off < 64; off <<= 1) { v += __shfl_xor(v, off); qq += __shfl_xor(qq, off); }
    if (lane == 0) { ps[wave][j] = v; ps[wave][DD + j] = qq; }
  }
  __syncthreads();
  if (tid < 2 * DD)
    atomAdd(&stats[tid], ps[0][tid] + ps[1][tid] + ps[2][tid] + ps[3][tid]);
  #pragma unroll
  for (int i = 0; i < 32; ++i) {
    int l = tid + i * 256;
    int r = l >> 5, c = l & 31;
    if (n0 + r < NN) g1[(size_t)(n0 + r) * DD + c] = us[r][c];
  }
}

// ---------------- K3b: finalize BN1 params
__global__ void k3b_bn(const float* __restrict__ stats, const float* __restrict__ gamma,
                       const float* __restrict__ beta, float* __restrict__ bnp) {
  int t = threadIdx.x;
  if (t < DD) {
    float mu = stats[t] * (1.f / NN);
    float var = stats[DD + t] * (1.f / NN) - mu * mu;
    bnp[t] = mu;
    bnp[DD + t] = rsqrtf(var + BN_EPS) * gamma[t];
    bnp[2 * DD + t] = beta[t];
  }
}

// ---------------- K6: g2 = relu((bn1(g1)+agg2)@w1+b1)@w2+b2 ; stats2
__global__ __launch_bounds__(256) void k6_mlp2(
    const float* __restrict__ g1, const float* __restrict__ agg,
    const float* __restrict__ bnp,
    const float* __restrict__ w1, const float* __restrict__ b1,
    const float* __restrict__ w2, const float* __restrict__ b2,
    float* __restrict__ g2, float* __restrict__ stats) {
  __shared__ float us[256][DD + 1];
  __shared__ float w1s[DD][DD];
  __shared__ float w2s[DD][DD];
  __shared__ float ps[4][2 * DD];
  const int tid = threadIdx.x;
  const int n0 = blockIdx.x * 256;
  for (int i = tid; i < DD * DD; i += 256) { w1s[i >> 5][i & 31] = w1[i]; w2s[i >> 5][i & 31] = w2[i]; }
  #pragma unroll
  for (int i = 0; i < 32; ++i) {
    int l = tid + i * 256;
    int r = l >> 5, c = l & 31;
    float v = 0.f;
    if (n0 + r < NN) {
      size_t gi = (size_t)(n0 + r) * DD + c;
      v = (g1[gi] - bnp[c]) * bnp[DD + c] + bnp[2 * DD + c] + agg[gi];
    }
    us[r][c] = v;
  }
  __syncthreads();
  float t1[DD];
  #pragma unroll
  for (int j = 0; j < DD; ++j) t1[j] = b1[j];
  #pragma unroll
  for (int k = 0; k < DD; ++k) {
    float uv = us[tid][k];
    #pragma unroll
    for (int j = 0; j < DD; ++j) t1[j] = fmaf(uv, w1s[k][j], t1[j]);
  }
  #pragma unroll
  for (int j = 0; j < DD; ++j) t1[j] = fmaxf(t1[j], 0.f);
  float g[DD];
  #pragma unroll
  for (int j = 0; j < DD; ++j) g[j] = b2[j];
  #pragma unroll
  for (int k = 0; k < DD; ++k) {
    float tv = t1[k];
    #pragma unroll
    for (int j = 0; j < DD; ++j) g[j] = fmaf(tv, w2s[k][j], g[j]);
  }
  bool valid = (n0 + tid) < NN;
  #pragma unroll
  for (int j = 0; j < DD; ++j) us[tid][j] = g[j];
  int wave = tid >> 6, lane = tid & 63;
  #pragma unroll
  for (int j = 0; j < DD; ++j) {
    float v = valid ? g[j] : 0.f;
    float qq = v * v;
    #pragma unroll
    for (int off = 1; off < 64; off <<= 1) { v += __shfl_xor(v, off); qq += __shfl_xor(qq, off); }
    if (lane == 0) { ps[wave][j] = v; ps[wave][DD + j] = qq; }
  }
  __syncthreads();
  if (tid < 2 * DD)
    atomAdd(&stats[tid], ps[0][tid] + ps[1][tid] + ps[2][tid] + ps[3][tid]);
  #pragma unroll
  for (int i = 0; i < 32; ++i) {
    int l = tid + i * 256;
    int r = l >> 5, c = l & 31;
    if (n0 + r < NN) g2[(size_t)(n0 + r) * DD + c] = us[r][c];
  }
}

// ---------------- K7: out = relu(bn2(g2)@fc1+b)@fc2+b
__global__ __launch_bounds__(256) void k7_head(
    const float* __restrict__ g2, const float* __restrict__ stats2,
    const float* __restrict__ bn2_g, const float* __restrict__ bn2_b,
    const float* __restrict__ fc1_w, const float* __restrict__ fc1_b,
    const float* __restrict__ fc2_w, const float* __restrict__ fc2_b,
    float* __restrict__ out) {
  __shared__ float buf[256 * 42];
  __shared__ float fc1s[DD * DD];
  __shared__ float fc2s[DD * CC];
  __shared__ float mu2[DD], rsg2[DD], bet2[DD];
  const int tid = threadIdx.x;
  const int n0 = blockIdx.x * 256;
  if (tid < DD) {
    float mu = stats2[tid] * (1.f / NN);
    float var = stats2[DD + tid] * (1.f / NN) - mu * mu;
    mu2[tid] = mu;
    rsg2[tid] = rsqrtf(var + BN_EPS) * bn2_g[tid];
    bet2[tid] = bn2_b[tid];
  }
  for (int i = tid; i < DD * DD; i += 256) fc1s[i] = fc1_w[i];
  for (int i = tid; i < DD * CC; i += 256) fc2s[i] = fc2_w[i];
  __syncthreads();
  #pragma unroll
  for (int i = 0; i < 32; ++i) {
    int l = tid + i * 256;
    int r = l >> 5, c = l & 31;
    float v = 0.f;
    if (n0 + r < NN) v = (g2[(size_t)(n0 + r) * DD + c] - mu2[c]) * rsg2[c] + bet2[c];
    buf[r * 33 + c] = v;
  }
  __syncthreads();
  float t[DD];
  #pragma unroll
  for (int j = 0; j < DD; ++j) t[j] = fc1_b[j];
  #pragma unroll
  for (int k = 0; k < DD; ++k) {
    float uv = buf[tid * 33 + k];
    #pragma unroll
    for (int j = 0; j < DD; ++j) t[j] = fmaf(uv, fc1s[k * DD + j], t[j]);
  }
  #pragma unroll
  for (int j = 0; j < DD; ++j) t[j] = fmaxf(t[j], 0.f);
  float o[CC];
  #pragma unroll
  for (int j = 0; j < CC; ++j) o[j] = fc2_b[j];
  #pragma unroll
  for (int k = 0; k < DD; ++k) {
    float tv = t[k];
    #pragma unroll
    for (int j = 0; j < CC; ++j) o[j] = fmaf(tv, fc2s[k * CC + j], o[j]);
  }
  __syncthreads();
  #pragma unroll
  for (int j = 0; j < CC; ++j) buf[tid * 42 + j] = o[j];
  __syncthreads();
  for (int i = 0; i < CC; ++i) {
    int l = tid + i * 256;
    int r = l / CC, c = l % CC;
    if (n0 + r < NN) out[(size_t)(n0 + r) * CC + c] = buf[r * 42 + c];
  }
}

extern "C" void kernel_launch(void* const* d_in, const int* in_sizes, int n_in,
                              void* d_out, int out_size, void* d_ws, size_t ws_size,
                              hipStream_t stream) {
  const float* x      = (const float*)d_in[0];
  const int*   ei     = (const int*)d_in[1];
  const float* lin1_w = (const float*)d_in[2];
  const float* lin1_b = (const float*)d_in[3];
  const float* nn1_w1 = (const float*)d_in[4];
  const float* nn1_b1 = (const float*)d_in[5];
  const float* nn1_w2 = (const float*)d_in[6];
  const float* nn1_b2 = (const float*)d_in[7];
  const float* bn1_g  = (const float*)d_in[8];
  const float* bn1_b  = (const float*)d_in[9];
  const float* nn2_w1 = (const float*)d_in[10];
  const float* nn2_b1 = (const float*)d_in[11];
  const float* nn2_w2 = (const float*)d_in[12];
  const float* nn2_b2 = (const float*)d_in[13];
  const float* bn2_g  = (const float*)d_in[14];
  const float* bn2_b  = (const float*)d_in[15];
  const float* fc1_w  = (const float*)d_in[16];
  const float* fc1_b  = (const float*)d_in[17];
  const float* fc2_w  = (const float*)d_in[18];
  const float* fc2_b  = (const float*)d_in[19];
  float* out = (float*)d_out;

  float* ws = (float*)d_ws;
  size_t nd = (size_t)NN * DD;
  float* A      = ws;            // z
  float* B      = ws + nd;       // agg1, then agg2
  float* Cb     = ws + 2 * nd;   // g1, then g2
  float* cvec   = ws + 3 * nd;
  float* stats1 = cvec + 32;
  float* bnp1   = stats1 + 64;
  float* stats2 = bnp1 + 96;
  unsigned short* Bhi = (unsigned short*)(stats2 + 64);     // 19456 shorts
  unsigned short* Blo = Bhi + KSTEPS * 2 * 64 * 8;          // 19456 shorts
  int*   rowstart = (int*)(Blo + KSTEPS * 2 * 64 * 8);      // NN+1
  int*   srcidx   = rowstart + (NN + 1);                    // NE
  int*   tsrc     = srcidx + NE;                            // NE
  unsigned char* tdst = (unsigned char*)(tsrc + NE);        // NE bytes
  int*   bcount   = (int*)(tdst + NE);                      // NB
  int*   bcursor  = bcount + NB;                            // NB
  int*   bbase    = bcursor + NB;                           // NB+1

  // bucketed CSR build
  hipMemsetAsync(bcount, 0, NB * sizeof(int), stream);
  kb_hist<<<SCB, 256, 0, stream>>>(ei, bcount);
  kb_scan<<<1, 512, 0, stream>>>(bcount, bbase, bcursor, rowstart);
  kb_scatter<<<SCB, 256, 0, stream>>>(ei, bcursor, tsrc, tdst);
  kb_fine<<<NB, 256, 0, stream>>>(bbase, tsrc, tdst, rowstart, srcidx);

  k0_prep<<<(KSTEPS * 32 * 32 + 255) / 256, 256, 0, stream>>>(
      lin1_w, lin1_b, nn1_w1, Bhi, Blo, cvec, stats1, stats2);
  k1_mfma<<<(NN / 16 + 3) / 4, 256, 0, stream>>>(x, Bhi, Blo, cvec, A);
  k_gather_t<false><<<(NN * 8 + 255) / 256, 256, 0, stream>>>(rowstart, srcidx, A, nullptr, B);
  k3_mlp1<<<(NN + 255) / 256, 256, 0, stream>>>(A, B, nn1_w2, nn1_b1, nn1_b2, Cb, stats1);
  k3b_bn<<<1, 64, 0, stream>>>(stats1, bn1_g, bn1_b, bnp1);
  k_gather_t<true><<<(NN * 8 + 255) / 256, 256, 0, stream>>>(rowstart, srcidx, Cb, bnp1, B);
  k6_mlp2<<<(NN + 255) / 256, 256, 0, stream>>>(Cb, B, bnp1, nn2_w1, nn2_b1, nn2_w2, nn2_b2, A, stats2);
  k7_head<<<(NN + 255) / 256, 256, 0, stream>>>(A, stats2, bn2_g, bn2_b, fc1_w, fc1_b, fc2_w, fc2_b, out);
}